// Round 7
// baseline (97.759 us; speedup 1.0000x reference)
//
#include <hip/hip_runtime.h>
#include <hip/hip_bf16.h>

#define NN     200000
#define FEATD  64
#define BN     4096
#define DEG    32
#define PP     2048
#define EMB    64
#define EPSV   1e-8f

// ws layout (float offsets)
#define WS_SC    0          // float4[NN]  {s0,s1,s2,norm}
#define WS_MISC  800000     // [0..2]=mean_pos  [4..6]=inv_pe
#define WS_LOSS  800064     // 24 slots, stride 32 floats (128B apart)
#define WS_RF    800832     // [3][BN][EMB]

// ---------------------------------------------------------------- kernel A
// sim = relu(F @ R) per node; store {dot(pe_r,sim)}_r, ||sim||.
// Register-blocked 4 nodes x 16 j per thread: each uniform ds_read_b128
// (rsim quad, broadcast) feeds 16 FMAs -> LDS pipe (~16k cyc/CU) below the
// VALU floor (~25k cyc/CU). j split over the block's 4 waves; partials
// combined via padded LDS (stride 17, conflict-free).
__global__ __launch_bounds__(256) void node_precompute(
    const float* __restrict__ features, const float* __restrict__ rsim,
    const float* __restrict__ pos_embs, float4* __restrict__ node_sc)
{
    __shared__ float4 rs4s[1024];      // [f][j4]  f*16 + j4
    __shared__ float4 pe4s[48];        // [r][j4]  r*16 + j4
    __shared__ float  red[4][64][17];  // [wave][lane][16 payload + pad]
    int t = threadIdx.x;
    const float4* rsim4 = (const float4*)rsim;
    for (int idx = t; idx < 1024; idx += 256) rs4s[idx] = rsim4[idx];
    if (t < 48) pe4s[t] = ((const float4*)pos_embs)[t];
    __syncthreads();

    int w = t >> 6;            // j-quarter (wave-uniform)
    int l = t & 63;
    int bs = blockIdx.x * 256;
    int n0 = bs + l * 4;
    int nc0 = min(n0 + 0, NN - 1), nc1 = min(n0 + 1, NN - 1);
    int nc2 = min(n0 + 2, NN - 1), nc3 = min(n0 + 3, NN - 1);
    const float4* fp0 = (const float4*)(features + (size_t)nc0 * FEATD);
    const float4* fp1 = (const float4*)(features + (size_t)nc1 * FEATD);
    const float4* fp2 = (const float4*)(features + (size_t)nc2 * FEATD);
    const float4* fp3 = (const float4*)(features + (size_t)nc3 * FEATD);

    float sim[4][16];
#pragma unroll
    for (int m = 0; m < 4; ++m)
#pragma unroll
        for (int j = 0; j < 16; ++j) sim[m][j] = 0.f;

    int jb = w * 4;            // float4 offset of this wave's j-quarter

    for (int f4 = 0; f4 < 16; ++f4) {
        float4 a0 = fp0[f4];   // 4 independent row loads (ILP)
        float4 a1 = fp1[f4];
        float4 a2 = fp2[f4];
        float4 a3 = fp3[f4];
#pragma unroll
        for (int u = 0; u < 4; ++u) {
            float x0 = (u==0)?a0.x:(u==1)?a0.y:(u==2)?a0.z:a0.w;
            float x1 = (u==0)?a1.x:(u==1)?a1.y:(u==2)?a1.z:a1.w;
            float x2 = (u==0)?a2.x:(u==1)?a2.y:(u==2)?a2.z:a2.w;
            float x3 = (u==0)?a3.x:(u==1)?a3.y:(u==2)?a3.z:a3.w;
            int frow = (f4 * 4 + u) * 16 + jb;
#pragma unroll
            for (int j4 = 0; j4 < 4; ++j4) {
                float4 r = rs4s[frow + j4];       // uniform -> broadcast
                sim[0][j4*4+0] += x0 * r.x; sim[0][j4*4+1] += x0 * r.y;
                sim[0][j4*4+2] += x0 * r.z; sim[0][j4*4+3] += x0 * r.w;
                sim[1][j4*4+0] += x1 * r.x; sim[1][j4*4+1] += x1 * r.y;
                sim[1][j4*4+2] += x1 * r.z; sim[1][j4*4+3] += x1 * r.w;
                sim[2][j4*4+0] += x2 * r.x; sim[2][j4*4+1] += x2 * r.y;
                sim[2][j4*4+2] += x2 * r.z; sim[2][j4*4+3] += x2 * r.w;
                sim[3][j4*4+0] += x3 * r.x; sim[3][j4*4+1] += x3 * r.y;
                sim[3][j4*4+2] += x3 * r.z; sim[3][j4*4+3] += x3 * r.w;
            }
        }
    }

    // per-thread partial epilogue on this j-quarter
#pragma unroll
    for (int m = 0; m < 4; ++m) {
        float q = 0.f, s0 = 0.f, s1 = 0.f, s2 = 0.f;
#pragma unroll
        for (int j4 = 0; j4 < 4; ++j4) {
            float4 p0 = pe4s[jb + j4];
            float4 p1 = pe4s[16 + jb + j4];
            float4 p2 = pe4s[32 + jb + j4];
#pragma unroll
            for (int c = 0; c < 4; ++c) {
                float v = fmaxf(sim[m][j4*4+c], 0.f);
                float pp0 = (c==0)?p0.x:(c==1)?p0.y:(c==2)?p0.z:p0.w;
                float pp1 = (c==0)?p1.x:(c==1)?p1.y:(c==2)?p1.z:p1.w;
                float pp2 = (c==0)?p2.x:(c==1)?p2.y:(c==2)?p2.z:p2.w;
                q  += v * v;
                s0 += v * pp0;
                s1 += v * pp1;
                s2 += v * pp2;
            }
        }
        red[w][l][m*4+0] = s0;
        red[w][l][m*4+1] = s1;
        red[w][l][m*4+2] = s2;
        red[w][l][m*4+3] = q;
    }
    __syncthreads();

    // combine the 4 j-quarters; thread t owns block-local node t
    int node = bs + t;
    if (node < NN) {
        int lq = t >> 2, sq = (t & 3) * 4;
        float c0 = 0.f, c1 = 0.f, c2 = 0.f, cq = 0.f;
#pragma unroll
        for (int w2 = 0; w2 < 4; ++w2) {
            c0 += red[w2][lq][sq + 0];
            c1 += red[w2][lq][sq + 1];
            c2 += red[w2][lq][sq + 2];
            cq += red[w2][lq][sq + 3];
        }
        node_sc[node] = make_float4(c0, c1, c2, sqrtf(cq));
    }
}

// ---------------------------------------------------------------- kernel B
// pe inverse norms, mean(pos_scores) per relation, zero loss slots.
__global__ __launch_bounds__(1024) void pos_stats(
    const int* __restrict__ pos_nodes, const float4* __restrict__ node_sc,
    const float* __restrict__ pos_embs, float* __restrict__ misc,
    float* __restrict__ lossacc)
{
    __shared__ float invpe_s[3];
    __shared__ float wsum[16][3];
    int t = threadIdx.x, wv = t >> 6, lane = t & 63;

    if (t < 24) lossacc[t * 32] = 0.f;           // zero spread loss slots

    // pe norms: waves 0..2 each own one pos_emb row
    float pv = (t < 192) ? pos_embs[t] : 0.f;
    float q = pv * pv;
#pragma unroll
    for (int off = 32; off; off >>= 1) q += __shfl_down(q, off);
    if (t < 192 && lane == 0) {
        float inv = 1.f / fmaxf(sqrtf(q), EPSV);
        invpe_s[wv] = inv;
        misc[4 + wv] = inv;
    }
    __syncthreads();

    float i0 = invpe_s[0], i1 = invpe_s[1], i2 = invpe_s[2];
    float s0 = 0.f, s1 = 0.f, s2 = 0.f;
    for (int p = t; p < PP; p += 1024) {
        int n = pos_nodes[p];
        float4 sc = node_sc[n];
        float invn = 1.f / fmaxf(sc.w, EPSV);
        s0 += sc.x * i0 * invn;
        s1 += sc.y * i1 * invn;
        s2 += sc.z * i2 * invn;
    }
#pragma unroll
    for (int off = 32; off; off >>= 1) {
        s0 += __shfl_down(s0, off);
        s1 += __shfl_down(s1, off);
        s2 += __shfl_down(s2, off);
    }
    if (lane == 0) { wsum[wv][0] = s0; wsum[wv][1] = s1; wsum[wv][2] = s2; }
    __syncthreads();
    if (t < 3) {
        float s = 0.f;
        for (int w = 0; w < 16; ++w) s += wsum[w][t];
        misc[t] = s / (float)PP;
    }
}

// ---------------------------------------------------------------- kernel C
// One wave per (b, r): score 32 neighbors, stable top-k, parallel 16-row
// feature aggregate, rfeat = relu(agg @ W_r) via uniform-LDS broadcast.
__global__ __launch_bounds__(256) void relation_agg(
    const int* __restrict__ n1, const int* __restrict__ n2, const int* __restrict__ n3,
    const float* __restrict__ features, const float4* __restrict__ node_sc,
    const float* __restrict__ W1, const float* __restrict__ W2, const float* __restrict__ W3,
    const float* __restrict__ misc, float* __restrict__ lossacc,
    float* __restrict__ rfeat, const int* __restrict__ smp)
{
    int r = blockIdx.y;
    const int*   neigh = (r == 0) ? n1 : (r == 1) ? n2 : n3;
    const float* W     = (r == 0) ? W1 : (r == 1) ? W2 : W3;
    int k = smp[0];
    int t = threadIdx.x;
    int wv = t >> 6, lane = t & 63;
    int b = blockIdx.x * 4 + wv;
    float inv_pe   = misc[4 + r];
    float mean_pos = misc[r];

    __shared__ int sel_ids[4][32];
    __shared__ float4 aggl[4][16];

    // ---- score phase (lanes 0-31)
    float s = -1e30f;
    int   n = 0;
    if (lane < 32) {
        n = neigh[b * DEG + lane];
        float4 sc = node_sc[n];
        float num = (r == 0) ? sc.x : (r == 1) ? sc.y : sc.z;
        s = num * inv_pe / fmaxf(sc.w, EPSV);
    }
    // stable rank among 32 scores (ties -> lower index), matches lax.top_k
    int cnt = 0;
#pragma unroll
    for (int d2 = 0; d2 < 32; ++d2) {
        float v = __shfl(s, d2);
        cnt += ((v > s) || (v == s && d2 < lane)) ? 1 : 0;
    }
    bool sel = (lane < 32) && (cnt < k);
    if (sel) sel_ids[wv][cnt] = n;       // rank = unique slot in [0,k)

    float lv = sel ? (s - mean_pos) * (s - mean_pos) : 0.f;
#pragma unroll
    for (int off = 32; off; off >>= 1) lv += __shfl_down(lv, off);
    if (lane == 0)
        atomicAdd(&lossacc[(r * 8 + (blockIdx.x & 7)) * 32], lv);
    // no __syncthreads: sel_ids producer/consumer are the same wave (lgkmcnt)

    // ---- aggregate phase: 16 lanes per row, 4 rows per load wavefront
    const float4* F = (const float4*)features;
    int col   = lane & 15;           // float4 index within a 64-float row
    int rbase = lane >> 4;           // 0..3
    float4 a = make_float4(0.f, 0.f, 0.f, 0.f);
    if (k == 16) {
        int nid0 = sel_ids[wv][rbase];
        int nid1 = sel_ids[wv][rbase + 4];
        int nid2 = sel_ids[wv][rbase + 8];
        int nid3 = sel_ids[wv][rbase + 12];
        float4 v0 = F[(size_t)nid0 * 16 + col];
        float4 v1 = F[(size_t)nid1 * 16 + col];
        float4 v2 = F[(size_t)nid2 * 16 + col];
        float4 v3 = F[(size_t)nid3 * 16 + col];
        a.x = v0.x + v1.x + v2.x + v3.x;
        a.y = v0.y + v1.y + v2.y + v3.y;
        a.z = v0.z + v1.z + v2.z + v3.z;
        a.w = v0.w + v1.w + v2.w + v3.w;
    } else {
        for (int row0 = 0; row0 < k; row0 += 4) {
            int row = row0 + rbase;
            if (row < k) {
                int nid = sel_ids[wv][row];
                float4 v = F[(size_t)nid * 16 + col];
                a.x += v.x; a.y += v.y; a.z += v.z; a.w += v.w;
            }
        }
    }
    // allreduce across the 4 row-groups (xor 16, 32)
#pragma unroll
    for (int off = 16; off <= 32; off <<= 1) {
        a.x += __shfl_xor(a.x, off);
        a.y += __shfl_xor(a.y, off);
        a.z += __shfl_xor(a.z, off);
        a.w += __shfl_xor(a.w, off);
    }
    float inv_k = 1.f / (float)k;
    a.x *= inv_k; a.y *= inv_k; a.z *= inv_k; a.w *= inv_k;

    // publish agg to LDS (lanes 0-15 hold cols 0..15)
    if (lane < 16) aggl[wv][lane] = a;
    // same-wave producer/consumer: compiler inserts lgkmcnt, no barrier

    // ---- rfeat[e=lane] = relu(sum_j agg[j] * W[j][e]) via uniform LDS reads
    float acc = 0.f;
#pragma unroll
    for (int j4 = 0; j4 < 16; ++j4) {
        float4 ag = aggl[wv][j4];            // wave-uniform -> broadcast
        acc += ag.x * W[(j4 * 4 + 0) * EMB + lane]
             + ag.y * W[(j4 * 4 + 1) * EMB + lane]
             + ag.z * W[(j4 * 4 + 2) * EMB + lane]
             + ag.w * W[(j4 * 4 + 3) * EMB + lane];
    }
    rfeat[((size_t)r * BN + b) * EMB + lane] = fmaxf(acc, 0.f);
}

// ---------------------------------------------------------------- kernel D
// combined[e][b] = relu(cat[b] . weight[:,e]).
// 512 blocks, b-tile = 8. weight read from GLOBAL, coalesced (lane = e,
// row stride 256B); cat in LDS (uniform broadcast).
#define CSTRIDE 264
__global__ __launch_bounds__(256) void final_mm(
    const int* __restrict__ nodes, const float* __restrict__ features,
    const float* __restrict__ rfeat, const float* __restrict__ weight,
    const float* __restrict__ lossacc, const int* __restrict__ smp,
    float* __restrict__ out)
{
    __shared__ float cat_b[8 * CSTRIDE];   // cat_b[bb][i]
    __shared__ float trans[8 * 65];        // output transpose tile
    __shared__ float ls[24];
    int t = threadIdx.x;
    int b0 = blockIdx.x * 8;

    if (blockIdx.x == 0 && t < 24) ls[t] = lossacc[t * 32];

    // stage cat columns: center features then 3 rfeat blocks
    for (int idx = t; idx < 512; idx += 256) {
        int bb = idx >> 6, f = idx & 63;
        cat_b[bb * CSTRIDE + f] = features[(size_t)nodes[b0 + bb] * FEATD + f];
    }
#pragma unroll
    for (int r = 0; r < 3; ++r)
        for (int idx = t; idx < 512; idx += 256) {
            int bb = idx >> 6, j = idx & 63;
            cat_b[bb * CSTRIDE + 64 + r * 64 + j] =
                rfeat[((size_t)r * BN + b0 + bb) * EMB + j];
        }
    __syncthreads();

    int wv = t >> 6, lane = t & 63;     // lane = e
    int bb0 = wv * 2;
    float acc0 = 0.f, acc1 = 0.f;
    const float* c0p = &cat_b[bb0 * CSTRIDE];
    const float* c1p = &cat_b[(bb0 + 1) * CSTRIDE];
    for (int i0 = 0; i0 < 256; i0 += 16) {
        float w[16];
#pragma unroll
        for (int u = 0; u < 16; ++u)
            w[u] = weight[(i0 + u) * EMB + lane];   // coalesced
#pragma unroll
        for (int u = 0; u < 16; ++u) {
            acc0 += w[u] * c0p[i0 + u];             // uniform LDS broadcast
            acc1 += w[u] * c1p[i0 + u];
        }
    }
    trans[bb0 * 65 + lane]       = fmaxf(acc0, 0.f);
    trans[(bb0 + 1) * 65 + lane] = fmaxf(acc1, 0.f);
    __syncthreads();

    // store: out[e][b0..b0+8]
    for (int idx = t; idx < 512; idx += 256) {
        int e = idx >> 3, bb = idx & 7;
        out[(size_t)e * BN + b0 + bb] = trans[bb * 65 + e];
    }

    if (blockIdx.x == 0 && t == 0) {
        int k = smp[0];
        float s = 0.f;
        for (int i = 0; i < 24; ++i) s += ls[i];
        out[(size_t)EMB * BN] = s / (3.f * (float)BN * (float)k);
    }
}

// ----------------------------------------------------------------
extern "C" void kernel_launch(void* const* d_in, const int* in_sizes, int n_in,
                              void* d_out, int out_size, void* d_ws, size_t ws_size,
                              hipStream_t stream) {
    const int*   nodes     = (const int*)  d_in[0];
    // d_in[1] labels: unused
    const int*   neigh1    = (const int*)  d_in[2];
    const int*   neigh2    = (const int*)  d_in[3];
    const int*   neigh3    = (const int*)  d_in[4];
    const int*   pos_nodes = (const int*)  d_in[5];
    const float* features  = (const float*)d_in[6];
    const float* weight    = (const float*)d_in[7];
    const float* rsim      = (const float*)d_in[8];
    const float* pos_embs  = (const float*)d_in[9];
    const float* W1        = (const float*)d_in[10];
    const float* W2        = (const float*)d_in[11];
    const float* W3        = (const float*)d_in[12];
    const int*   smp       = (const int*)  d_in[13];
    float* out = (float*)d_out;
    float* ws  = (float*)d_ws;

    float4* node_sc = (float4*)(ws + WS_SC);
    float*  misc    = ws + WS_MISC;
    float*  lossacc = ws + WS_LOSS;
    float*  rfeat   = ws + WS_RF;

    node_precompute<<<dim3((NN + 255) / 256), dim3(256), 0, stream>>>(
        features, rsim, pos_embs, node_sc);
    pos_stats<<<dim3(1), dim3(1024), 0, stream>>>(
        pos_nodes, node_sc, pos_embs, misc, lossacc);
    relation_agg<<<dim3(BN / 4, 3), dim3(256), 0, stream>>>(
        neigh1, neigh2, neigh3, features, node_sc, W1, W2, W3,
        misc, lossacc, rfeat, smp);
    final_mm<<<dim3(BN / 8), dim3(256), 0, stream>>>(
        nodes, features, rfeat, weight, lossacc, smp, out);
}

// Round 8
// 85.944 us; speedup vs baseline: 1.1375x; 1.1375x over previous
//
#include <hip/hip_runtime.h>
#include <hip/hip_bf16.h>

#define NN     200000
#define FEATD  64
#define BN     4096
#define DEG    32
#define PP     2048
#define EMB    64
#define EPSV   1e-8f

// ws layout (float offsets)
#define WS_SC    0          // float4[NN]  {s0,s1,s2,norm}
#define WS_MISC  800000     // [0..2]=mean_pos  [4..6]=inv_pe
#define WS_LOSS  800064     // 24 slots, stride 32 floats (128B apart)
#define WS_RF    800832     // [3][BN][EMB]

// ---------------------------------------------------------------- kernel A
// sim = relu(F @ R) per node; store {dot(pe_r,sim)}_r, ||sim||.
// 128-node tile staged in LDS via COALESCED loads (the r4-r7 kernels all
// died on 256B-lane-stride gathers: 64 cache lines per load instruction).
// f4-major swizzled layout col = n ^ f4 ^ ((n>>3)&7): staging writes <=2-way,
// compute reads conflict-free (8 distinct bank-quads x 8-lane broadcast).
// Thread = 8 nodes x 8 j: per f4, 16 ds_read_b128 feed 256 FMAs.
// No barriers in the hot loop. LDS 49KB -> 3 blocks/CU.
__global__ __launch_bounds__(128) void node_precompute(
    const float* __restrict__ features, const float* __restrict__ rsim,
    const float* __restrict__ pos_embs, float4* __restrict__ node_sc)
{
    __shared__ float4 fT4[16 * 128];   // [f4][col] swizzled, 32KB
    __shared__ float4 R4s[1024];       // [f][j4], 16KB
    __shared__ float4 pe4s[48];        // [r][j4]
    int t = threadIdx.x;
    const float4* Gf = (const float4*)features;
    const float4* rsim4 = (const float4*)rsim;

    for (int idx = t; idx < 1024; idx += 128) R4s[idx] = rsim4[idx];
    if (t < 48) pe4s[t] = ((const float4*)pos_embs)[t];

    int base = blockIdx.x * (128 * 16);
#pragma unroll
    for (int k = 0; k < 16; ++k) {
        int idx = k * 128 + t;                   // coalesced: 2KB/instr
        int gidx = base + idx;
        float4 v = Gf[min(gidx, NN * 16 - 1)];   // tail clamp (junk ok)
        int node = idx >> 4, f4 = idx & 15;
        int col = node ^ f4 ^ ((node >> 3) & 7);
        fT4[f4 * 128 + col] = v;
    }
    __syncthreads();

    int w = t >> 6, l = t & 63;
    int g8 = l >> 3;             // node-group within wave
    int jo = l & 7;              // j-octant
    int nb = w * 64 + g8 * 8;    // local node base (8 nodes per thread)
    int jo2 = jo * 2;

    float sim[8][8];
#pragma unroll
    for (int m = 0; m < 8; ++m)
#pragma unroll
        for (int j = 0; j < 8; ++j) sim[m][j] = 0.f;

    for (int f4 = 0; f4 < 16; ++f4) {
        float4 fv[8];
#pragma unroll
        for (int m = 0; m < 8; ++m) {
            int n = nb + m;
            fv[m] = fT4[f4 * 128 + (n ^ f4 ^ g8)];   // (n>>3)&7 == g8
        }
#pragma unroll
        for (int u = 0; u < 4; ++u) {
            float4 r0 = R4s[(f4 * 4 + u) * 16 + jo2];
            float4 r1 = R4s[(f4 * 4 + u) * 16 + jo2 + 1];
#pragma unroll
            for (int m = 0; m < 8; ++m) {
                float x = (u == 0) ? fv[m].x : (u == 1) ? fv[m].y
                        : (u == 2) ? fv[m].z : fv[m].w;
                sim[m][0] += x * r0.x; sim[m][1] += x * r0.y;
                sim[m][2] += x * r0.z; sim[m][3] += x * r0.w;
                sim[m][4] += x * r1.x; sim[m][5] += x * r1.y;
                sim[m][6] += x * r1.z; sim[m][7] += x * r1.w;
            }
        }
    }

    // per-thread epilogue on its 8-j slice
    float red[8][4];
#pragma unroll
    for (int m = 0; m < 8; ++m) {
        float q = 0.f, s0 = 0.f, s1 = 0.f, s2 = 0.f;
#pragma unroll
        for (int j4 = 0; j4 < 2; ++j4) {
            float4 p0 = pe4s[jo2 + j4];
            float4 p1 = pe4s[16 + jo2 + j4];
            float4 p2 = pe4s[32 + jo2 + j4];
#pragma unroll
            for (int c = 0; c < 4; ++c) {
                float v = fmaxf(sim[m][j4 * 4 + c], 0.f);
                float pp0 = (c==0)?p0.x:(c==1)?p0.y:(c==2)?p0.z:p0.w;
                float pp1 = (c==0)?p1.x:(c==1)?p1.y:(c==2)?p1.z:p1.w;
                float pp2 = (c==0)?p2.x:(c==1)?p2.y:(c==2)?p2.z:p2.w;
                q += v * v; s0 += v * pp0; s1 += v * pp1; s2 += v * pp2;
            }
        }
        red[m][0] = s0; red[m][1] = s1; red[m][2] = s2; red[m][3] = q;
    }
    // allreduce across the 8 jo-lanes of each node-group
#pragma unroll
    for (int o = 1; o < 8; o <<= 1)
#pragma unroll
        for (int m = 0; m < 8; ++m)
#pragma unroll
            for (int c = 0; c < 4; ++c)
                red[m][c] += __shfl_xor(red[m][c], o);

    // lane jo writes node nb+jo; static-index select (no dynamic red[jo])
    float r0 = 0.f, r1 = 0.f, r2 = 0.f, rq = 0.f;
#pragma unroll
    for (int m = 0; m < 8; ++m) {
        bool pick = (jo == m);
        r0 = pick ? red[m][0] : r0;
        r1 = pick ? red[m][1] : r1;
        r2 = pick ? red[m][2] : r2;
        rq = pick ? red[m][3] : rq;
    }
    int node = blockIdx.x * 128 + nb + jo;
    if (node < NN)
        node_sc[node] = make_float4(r0, r1, r2, sqrtf(rq));
}

// ---------------------------------------------------------------- kernel B
// pe inverse norms, mean(pos_scores) per relation, zero loss slots.
__global__ __launch_bounds__(1024) void pos_stats(
    const int* __restrict__ pos_nodes, const float4* __restrict__ node_sc,
    const float* __restrict__ pos_embs, float* __restrict__ misc,
    float* __restrict__ lossacc)
{
    __shared__ float invpe_s[3];
    __shared__ float wsum[16][3];
    int t = threadIdx.x, wv = t >> 6, lane = t & 63;

    if (t < 24) lossacc[t * 32] = 0.f;           // zero spread loss slots

    // pe norms: waves 0..2 each own one pos_emb row
    float pv = (t < 192) ? pos_embs[t] : 0.f;
    float q = pv * pv;
#pragma unroll
    for (int off = 32; off; off >>= 1) q += __shfl_down(q, off);
    if (t < 192 && lane == 0) {
        float inv = 1.f / fmaxf(sqrtf(q), EPSV);
        invpe_s[wv] = inv;
        misc[4 + wv] = inv;
    }
    __syncthreads();

    float i0 = invpe_s[0], i1 = invpe_s[1], i2 = invpe_s[2];
    float s0 = 0.f, s1 = 0.f, s2 = 0.f;
    for (int p = t; p < PP; p += 1024) {
        int n = pos_nodes[p];
        float4 sc = node_sc[n];
        float invn = 1.f / fmaxf(sc.w, EPSV);
        s0 += sc.x * i0 * invn;
        s1 += sc.y * i1 * invn;
        s2 += sc.z * i2 * invn;
    }
#pragma unroll
    for (int off = 32; off; off >>= 1) {
        s0 += __shfl_down(s0, off);
        s1 += __shfl_down(s1, off);
        s2 += __shfl_down(s2, off);
    }
    if (lane == 0) { wsum[wv][0] = s0; wsum[wv][1] = s1; wsum[wv][2] = s2; }
    __syncthreads();
    if (t < 3) {
        float s = 0.f;
        for (int w = 0; w < 16; ++w) s += wsum[w][t];
        misc[t] = s / (float)PP;
    }
}

// ---------------------------------------------------------------- kernel C
// One wave per (b, r): score 32 neighbors, stable top-k, parallel 16-row
// feature aggregate, rfeat = relu(agg @ W_r) via uniform-LDS broadcast.
__global__ __launch_bounds__(256) void relation_agg(
    const int* __restrict__ n1, const int* __restrict__ n2, const int* __restrict__ n3,
    const float* __restrict__ features, const float4* __restrict__ node_sc,
    const float* __restrict__ W1, const float* __restrict__ W2, const float* __restrict__ W3,
    const float* __restrict__ misc, float* __restrict__ lossacc,
    float* __restrict__ rfeat, const int* __restrict__ smp)
{
    int r = blockIdx.y;
    const int*   neigh = (r == 0) ? n1 : (r == 1) ? n2 : n3;
    const float* W     = (r == 0) ? W1 : (r == 1) ? W2 : W3;
    int k = smp[0];
    int t = threadIdx.x;
    int wv = t >> 6, lane = t & 63;
    int b = blockIdx.x * 4 + wv;
    float inv_pe   = misc[4 + r];
    float mean_pos = misc[r];

    __shared__ int sel_ids[4][32];
    __shared__ float4 aggl[4][16];

    // ---- score phase (lanes 0-31)
    float s = -1e30f;
    int   n = 0;
    if (lane < 32) {
        n = neigh[b * DEG + lane];
        float4 sc = node_sc[n];
        float num = (r == 0) ? sc.x : (r == 1) ? sc.y : sc.z;
        s = num * inv_pe / fmaxf(sc.w, EPSV);
    }
    // stable rank among 32 scores (ties -> lower index), matches lax.top_k
    int cnt = 0;
#pragma unroll
    for (int d2 = 0; d2 < 32; ++d2) {
        float v = __shfl(s, d2);
        cnt += ((v > s) || (v == s && d2 < lane)) ? 1 : 0;
    }
    bool sel = (lane < 32) && (cnt < k);
    if (sel) sel_ids[wv][cnt] = n;       // rank = unique slot in [0,k)

    float lv = sel ? (s - mean_pos) * (s - mean_pos) : 0.f;
#pragma unroll
    for (int off = 32; off; off >>= 1) lv += __shfl_down(lv, off);
    if (lane == 0)
        atomicAdd(&lossacc[(r * 8 + (blockIdx.x & 7)) * 32], lv);
    // no __syncthreads: sel_ids producer/consumer are the same wave (lgkmcnt)

    // ---- aggregate phase: 16 lanes per row, 4 rows per load wavefront
    const float4* F = (const float4*)features;
    int col   = lane & 15;           // float4 index within a 64-float row
    int rbase = lane >> 4;           // 0..3
    float4 a = make_float4(0.f, 0.f, 0.f, 0.f);
    if (k == 16) {
        int nid0 = sel_ids[wv][rbase];
        int nid1 = sel_ids[wv][rbase + 4];
        int nid2 = sel_ids[wv][rbase + 8];
        int nid3 = sel_ids[wv][rbase + 12];
        float4 v0 = F[(size_t)nid0 * 16 + col];
        float4 v1 = F[(size_t)nid1 * 16 + col];
        float4 v2 = F[(size_t)nid2 * 16 + col];
        float4 v3 = F[(size_t)nid3 * 16 + col];
        a.x = v0.x + v1.x + v2.x + v3.x;
        a.y = v0.y + v1.y + v2.y + v3.y;
        a.z = v0.z + v1.z + v2.z + v3.z;
        a.w = v0.w + v1.w + v2.w + v3.w;
    } else {
        for (int row0 = 0; row0 < k; row0 += 4) {
            int row = row0 + rbase;
            if (row < k) {
                int nid = sel_ids[wv][row];
                float4 v = F[(size_t)nid * 16 + col];
                a.x += v.x; a.y += v.y; a.z += v.z; a.w += v.w;
            }
        }
    }
    // allreduce across the 4 row-groups (xor 16, 32)
#pragma unroll
    for (int off = 16; off <= 32; off <<= 1) {
        a.x += __shfl_xor(a.x, off);
        a.y += __shfl_xor(a.y, off);
        a.z += __shfl_xor(a.z, off);
        a.w += __shfl_xor(a.w, off);
    }
    float inv_k = 1.f / (float)k;
    a.x *= inv_k; a.y *= inv_k; a.z *= inv_k; a.w *= inv_k;

    // publish agg to LDS (lanes 0-15 hold cols 0..15)
    if (lane < 16) aggl[wv][lane] = a;
    // same-wave producer/consumer: compiler inserts lgkmcnt, no barrier

    // ---- rfeat[e=lane] = relu(sum_j agg[j] * W[j][e]) via uniform LDS reads
    float acc = 0.f;
#pragma unroll
    for (int j4 = 0; j4 < 16; ++j4) {
        float4 ag = aggl[wv][j4];            // wave-uniform -> broadcast
        acc += ag.x * W[(j4 * 4 + 0) * EMB + lane]
             + ag.y * W[(j4 * 4 + 1) * EMB + lane]
             + ag.z * W[(j4 * 4 + 2) * EMB + lane]
             + ag.w * W[(j4 * 4 + 3) * EMB + lane];
    }
    rfeat[((size_t)r * BN + b) * EMB + lane] = fmaxf(acc, 0.f);
}

// ---------------------------------------------------------------- kernel D
// combined[e][b] = relu(cat[b] . weight[:,e]).
// 512 blocks, b-tile = 8. weight read from GLOBAL, coalesced (lane = e,
// row stride 256B); cat in LDS (uniform broadcast).
#define CSTRIDE 264
__global__ __launch_bounds__(256) void final_mm(
    const int* __restrict__ nodes, const float* __restrict__ features,
    const float* __restrict__ rfeat, const float* __restrict__ weight,
    const float* __restrict__ lossacc, const int* __restrict__ smp,
    float* __restrict__ out)
{
    __shared__ float cat_b[8 * CSTRIDE];   // cat_b[bb][i]
    __shared__ float trans[8 * 65];        // output transpose tile
    __shared__ float ls[24];
    int t = threadIdx.x;
    int b0 = blockIdx.x * 8;

    if (blockIdx.x == 0 && t < 24) ls[t] = lossacc[t * 32];

    // stage cat columns: center features then 3 rfeat blocks
    for (int idx = t; idx < 512; idx += 256) {
        int bb = idx >> 6, f = idx & 63;
        cat_b[bb * CSTRIDE + f] = features[(size_t)nodes[b0 + bb] * FEATD + f];
    }
#pragma unroll
    for (int r = 0; r < 3; ++r)
        for (int idx = t; idx < 512; idx += 256) {
            int bb = idx >> 6, j = idx & 63;
            cat_b[bb * CSTRIDE + 64 + r * 64 + j] =
                rfeat[((size_t)r * BN + b0 + bb) * EMB + j];
        }
    __syncthreads();

    int wv = t >> 6, lane = t & 63;     // lane = e
    int bb0 = wv * 2;
    float acc0 = 0.f, acc1 = 0.f;
    const float* c0p = &cat_b[bb0 * CSTRIDE];
    const float* c1p = &cat_b[(bb0 + 1) * CSTRIDE];
    for (int i0 = 0; i0 < 256; i0 += 16) {
        float w[16];
#pragma unroll
        for (int u = 0; u < 16; ++u)
            w[u] = weight[(i0 + u) * EMB + lane];   // coalesced
#pragma unroll
        for (int u = 0; u < 16; ++u) {
            acc0 += w[u] * c0p[i0 + u];             // uniform LDS broadcast
            acc1 += w[u] * c1p[i0 + u];
        }
    }
    trans[bb0 * 65 + lane]       = fmaxf(acc0, 0.f);
    trans[(bb0 + 1) * 65 + lane] = fmaxf(acc1, 0.f);
    __syncthreads();

    // store: out[e][b0..b0+8]
    for (int idx = t; idx < 512; idx += 256) {
        int e = idx >> 3, bb = idx & 7;
        out[(size_t)e * BN + b0 + bb] = trans[bb * 65 + e];
    }

    if (blockIdx.x == 0 && t == 0) {
        int k = smp[0];
        float s = 0.f;
        for (int i = 0; i < 24; ++i) s += ls[i];
        out[(size_t)EMB * BN] = s / (3.f * (float)BN * (float)k);
    }
}

// ----------------------------------------------------------------
extern "C" void kernel_launch(void* const* d_in, const int* in_sizes, int n_in,
                              void* d_out, int out_size, void* d_ws, size_t ws_size,
                              hipStream_t stream) {
    const int*   nodes     = (const int*)  d_in[0];
    // d_in[1] labels: unused
    const int*   neigh1    = (const int*)  d_in[2];
    const int*   neigh2    = (const int*)  d_in[3];
    const int*   neigh3    = (const int*)  d_in[4];
    const int*   pos_nodes = (const int*)  d_in[5];
    const float* features  = (const float*)d_in[6];
    const float* weight    = (const float*)d_in[7];
    const float* rsim      = (const float*)d_in[8];
    const float* pos_embs  = (const float*)d_in[9];
    const float* W1        = (const float*)d_in[10];
    const float* W2        = (const float*)d_in[11];
    const float* W3        = (const float*)d_in[12];
    const int*   smp       = (const int*)  d_in[13];
    float* out = (float*)d_out;
    float* ws  = (float*)d_ws;

    float4* node_sc = (float4*)(ws + WS_SC);
    float*  misc    = ws + WS_MISC;
    float*  lossacc = ws + WS_LOSS;
    float*  rfeat   = ws + WS_RF;

    node_precompute<<<dim3((NN + 127) / 128), dim3(128), 0, stream>>>(
        features, rsim, pos_embs, node_sc);
    pos_stats<<<dim3(1), dim3(1024), 0, stream>>>(
        pos_nodes, node_sc, pos_embs, misc, lossacc);
    relation_agg<<<dim3(BN / 4, 3), dim3(256), 0, stream>>>(
        neigh1, neigh2, neigh3, features, node_sc, W1, W2, W3,
        misc, lossacc, rfeat, smp);
    final_mm<<<dim3(BN / 8), dim3(256), 0, stream>>>(
        nodes, features, rfeat, weight, lossacc, smp, out);
}